// Round 4
// baseline (66.118 us; speedup 1.0000x reference)
//
#include <hip/hip_runtime.h>
#include <stdint.h>

#define BATCH   32768
#define NBITS   512
#define NWORDS  512          // BATCH / 64
#define NSLICE  16           // K-split: 136 tiles * 16 = 2176 blocks (~8.5/CU)
#define SW      32           // words per slice = NWORDS / NSLICE
#define NT32    136          // 16x17/2 lower-triangle of 32x32 tiles

typedef unsigned long long u64;

// ---------------------------------------------------------------------------
// Pass 1: bit-pack + build f64 log table.
// packed[w*NBITS + col] = 64-bit mask of rows w*64..w*64+63 for column col.
// ---------------------------------------------------------------------------
__global__ __launch_bounds__(256) void pack_kernel(const float* __restrict__ bits,
                                                   u64* __restrict__ packed,
                                                   double* __restrict__ lg) {
    const int gid = blockIdx.x * 256 + threadIdx.x;   // 0..65535

    // f64 log table for the MI epilogue (args are integers 0..32768)
    if (gid <= BATCH) lg[gid] = (gid > 0) ? log((double)gid) : 0.0;

    const int wv   = threadIdx.x >> 6;
    const int lane = threadIdx.x & 63;
    const int gw   = blockIdx.x * 4 + wv;     // 0..1023
    const int cg   = gw & 1;                  // column half (0..1)
    const int w    = gw >> 1;                 // word 0..511
    const int c0   = cg * 256 + lane * 4;

    u64 m0 = 0, m1 = 0, m2 = 0, m3 = 0;
    const float* base = bits + (size_t)w * 64 * NBITS + c0;
#pragma unroll 16
    for (int r = 0; r < 64; ++r) {
        float4 v = *reinterpret_cast<const float4*>(base + (size_t)r * NBITS);
        const u64 b = 1ull << r;
        if (v.x > 0.0f) m0 |= b;
        if (v.y > 0.0f) m1 |= b;
        if (v.z > 0.0f) m2 |= b;
        if (v.w > 0.0f) m3 |= b;
    }
    u64* dst = packed + (size_t)w * NBITS + c0;
    dst[0] = m0; dst[1] = m1; dst[2] = m2; dst[3] = m3;
}

// ---------------------------------------------------------------------------
// Pass 1b: column 1-counts. c1[c] = popcount of column c. Coalesced u64 reads.
// ---------------------------------------------------------------------------
__global__ __launch_bounds__(256) void c1_kernel(const u64* __restrict__ packed,
                                                 int* __restrict__ c1) {
    const int c = blockIdx.x * 256 + threadIdx.x;   // 0..511
    int s = 0;
#pragma unroll 8
    for (int w = 0; w < NWORDS; ++w)
        s += __popcll(packed[(size_t)w * NBITS + c]);
    c1[c] = s;
}

// ---------------------------------------------------------------------------
// Pass 2: partial Gram. Block = (tile t of 136, slice s of 16).
// 32x32 tile, 2x2 register tile per thread; column index on the fast thread
// dim -> int2-coalesced writes. 2176 blocks at 16 KB LDS -> ~8 blocks/CU,
// 32 waves/CU: latency hidden by TLP. Plain stores (no atomics, no zeroing).
// ---------------------------------------------------------------------------
__global__ __launch_bounds__(256) void gram_kernel(const u64* __restrict__ packed,
                                                   int* __restrict__ Cp) {
    __shared__ u64 ldsI[SW][32];
    __shared__ u64 ldsJ[SW][32];

    const int s = blockIdx.x & (NSLICE - 1);  // K-slice 0..15
    const int t = blockIdx.x >> 4;            // tile 0..135
    int bi = (int)((sqrtf(8.0f * (float)t + 1.0f) - 1.0f) * 0.5f);
    while ((bi + 1) * (bi + 2) / 2 <= t) ++bi;
    while (bi * (bi + 1) / 2 > t) --bi;
    const int bj = t - bi * (bi + 1) / 2;

    const int i0 = bi * 32, j0 = bj * 32;
    const int w0 = s * SW;
    const bool diag = (bi == bj);

    // stage this slice's 32 words x 32 cols per side (8 KB each)
    for (int q = threadIdx.x; q < SW * 16; q += 256) {
        const int wo = q >> 4, cp = (q & 15) * 2;
        const size_t g = (size_t)(w0 + wo) * NBITS;
        *reinterpret_cast<ulonglong2*>(&ldsI[wo][cp]) =
            *reinterpret_cast<const ulonglong2*>(&packed[g + i0 + cp]);
        if (!diag)
            *reinterpret_cast<ulonglong2*>(&ldsJ[wo][cp]) =
                *reinterpret_cast<const ulonglong2*>(&packed[g + j0 + cp]);
    }
    __syncthreads();

    const int tj2 = (threadIdx.x & 15) * 2;   // col within tile (fast dim)
    const int ti2 = (threadIdx.x >> 4) * 2;   // row within tile
    const u64 (*BJ)[32] = diag ? ldsI : ldsJ;

    int a00 = 0, a01 = 0, a10 = 0, a11 = 0;
#pragma unroll
    for (int w = 0; w < SW; ++w) {
        const u64 r0 = ldsI[w][ti2], r1 = ldsI[w][ti2 + 1];
        const u64 c0 = BJ[w][tj2],   c1v = BJ[w][tj2 + 1];
        a00 += __popcll(r0 & c0); a01 += __popcll(r0 & c1v);
        a10 += __popcll(r1 & c0); a11 += __popcll(r1 & c1v);
    }

    int* out = Cp + (size_t)s * NBITS * NBITS;
    const int row = i0 + ti2, col = j0 + tj2;
    *reinterpret_cast<int2*>(&out[(size_t)row * NBITS + col])       = make_int2(a00, a01);
    *reinterpret_cast<int2*>(&out[(size_t)(row + 1) * NBITS + col]) = make_int2(a10, a11);
}

// ---------------------------------------------------------------------------
// Pass 3: per-pair MI terms. Block i, thread j (+256). n11 = coalesced sum of
// 16 slice partials of row i; marginals from c1 table. Log-table epilogue,
// deterministic block reduction.
// ---------------------------------------------------------------------------
__global__ __launch_bounds__(256) void mi_kernel(const int* __restrict__ Cp,
                                                 const int* __restrict__ c1,
                                                 const double* __restrict__ lg,
                                                 double* __restrict__ bsum,
                                                 int* __restrict__ bcnt) {
    const double invB = 1.0 / (double)BATCH;
    const int i = blockIdx.x;
    const int ci = c1[i];
    const double lgB = lg[BATCH];
    double lsum = 0.0;
    int lcnt = 0;

#pragma unroll
    for (int half = 0; half < 2; ++half) {
        const int j = half * 256 + threadIdx.x;
        if (j < i) {
            int n11 = 0;
#pragma unroll
            for (int s = 0; s < NSLICE; ++s)
                n11 += Cp[(size_t)s * NBITS * NBITS + (size_t)i * NBITS + j];
            const int cj = c1[j];

            const int pim[2] = {BATCH - ci, ci};
            const int pjn[2] = {BATCH - cj, cj};
            const int nmn[2][2] = {{BATCH - ci - cj + n11, cj - n11},
                                   {ci - n11, n11}};
#pragma unroll
            for (int m = 0; m < 2; ++m)
#pragma unroll
                for (int n = 0; n < 2; ++n) {
                    const int c_mn = nmn[m][n];
                    if (c_mn > 0 && pim[m] > 0 && pjn[n] > 0) {
                        lsum += (double)c_mn * invB *
                                (lg[c_mn] + lgB - lg[pim[m]] - lg[pjn[n]]);
                        ++lcnt;
                    }
                }
        }
    }

    __shared__ double ssum[256];
    __shared__ int scnt[256];
    ssum[threadIdx.x] = lsum;
    scnt[threadIdx.x] = lcnt;
    __syncthreads();
    for (int off = 128; off > 0; off >>= 1) {
        if (threadIdx.x < off) {
            ssum[threadIdx.x] += ssum[threadIdx.x + off];
            scnt[threadIdx.x] += scnt[threadIdx.x + off];
        }
        __syncthreads();
    }
    if (threadIdx.x == 0) { bsum[blockIdx.x] = ssum[0]; bcnt[blockIdx.x] = scnt[0]; }
}

// ---------------------------------------------------------------------------
// Pass 4: final deterministic reduce, out = sum / cnt.
// ---------------------------------------------------------------------------
__global__ __launch_bounds__(256) void final_kernel(const double* __restrict__ bsum,
                                                    const int* __restrict__ bcnt,
                                                    float* __restrict__ out,
                                                    int nblocks) {
    __shared__ double ssum[256];
    __shared__ int scnt[256];
    double s = 0.0; int c = 0;
    for (int k = threadIdx.x; k < nblocks; k += 256) { s += bsum[k]; c += bcnt[k]; }
    ssum[threadIdx.x] = s;
    scnt[threadIdx.x] = c;
    __syncthreads();
    for (int off = 128; off > 0; off >>= 1) {
        if (threadIdx.x < off) {
            ssum[threadIdx.x] += ssum[threadIdx.x + off];
            scnt[threadIdx.x] += scnt[threadIdx.x + off];
        }
        __syncthreads();
    }
    if (threadIdx.x == 0) out[0] = (float)(ssum[0] / (double)scnt[0]);
}

// ---------------------------------------------------------------------------
extern "C" void kernel_launch(void* const* d_in, const int* in_sizes, int n_in,
                              void* d_out, int out_size, void* d_ws, size_t ws_size,
                              hipStream_t stream) {
    const float* bits = (const float*)d_in[0];
    char* ws = (char*)d_ws;
    u64*    packed = (u64*)ws;                                 // 2 MB
    int*    Cp     = (int*)(ws + (2u << 20));                  // 16 x 1 MB
    double* lg     = (double*)(ws + (18u << 20));              // 256 KB + 8 B
    int*    c1     = (int*)(ws + (18u << 20) + (512u << 10));  // 2 KB
    double* bsum   = (double*)(ws + (18u << 20) + (576u << 10)); // 4 KB
    int*    bcnt   = (int*)(ws + (18u << 20) + (640u << 10));  // 2 KB

    pack_kernel<<<256, 256, 0, stream>>>(bits, packed, lg);
    c1_kernel<<<2, 256, 0, stream>>>(packed, c1);
    gram_kernel<<<NT32 * NSLICE, 256, 0, stream>>>(packed, Cp);
    mi_kernel<<<NBITS, 256, 0, stream>>>(Cp, c1, lg, bsum, bcnt);
    final_kernel<<<1, 256, 0, stream>>>(bsum, bcnt, (float*)d_out, NBITS);
}

// Round 5
// 43.547 us; speedup vs baseline: 1.5183x; 1.5183x over previous
//
#include <hip/hip_runtime.h>
#include <stdint.h>

#define BATCH   32768
#define NBITS   512
#define NWORDS  512          // BATCH / 64
#define NSLICE  32           // K-split: 36 tiles * 32 = 1152 blocks (~4.5/CU)
#define SW      16           // words per slice = NWORDS / NSLICE
#define NTILE   36           // 8x8 lower-triangle of 64x64 tiles

typedef unsigned long long u64;

// ---------------------------------------------------------------------------
// Pass 1: bit-pack + f64 log table + zero c1.
// 2048 wave-tasks (2 waves/SIMD): wave = (word w, column-quarter q); lane
// reads float2 (512 B per wave-load), builds two u64 row-masks, ulonglong2
// store. Memory-bound: 64 MB read @ ~6.3 TB/s -> ~10.5 us.
// ---------------------------------------------------------------------------
__global__ __launch_bounds__(256) void pack_kernel(const float* __restrict__ bits,
                                                   u64* __restrict__ packed,
                                                   double* __restrict__ lg,
                                                   int* __restrict__ c1) {
    const int gid = blockIdx.x * 256 + threadIdx.x;   // 0..131071

    // f64 log table for the MI epilogue (args are integers 0..32768)
    if (gid <= BATCH) lg[gid] = (gid > 0) ? log((double)gid) : 0.0;
    if (gid < NBITS) c1[gid] = 0;

    const int wv   = threadIdx.x >> 6;
    const int lane = threadIdx.x & 63;
    const int gw   = blockIdx.x * 4 + wv;     // 0..2047
    const int w    = gw >> 2;                 // word 0..511
    const int q    = gw & 3;                  // column quarter
    const int c0   = q * 128 + lane * 2;

    u64 m0 = 0, m1 = 0;
    const float* base = bits + (size_t)w * 64 * NBITS + c0;
#pragma unroll 16
    for (int r = 0; r < 64; ++r) {
        float2 v = *reinterpret_cast<const float2*>(base + (size_t)r * NBITS);
        const u64 b = 1ull << r;
        if (v.x > 0.0f) m0 |= b;
        if (v.y > 0.0f) m1 |= b;
    }
    ulonglong2 st; st.x = m0; st.y = m1;
    *reinterpret_cast<ulonglong2*>(&packed[(size_t)w * NBITS + c0]) = st;
}

// ---------------------------------------------------------------------------
// Pass 2: partial Gram. Block = (tile t of 36, slice s of 32).
// 64x64 tile, 4x4 register tile with interleaved columns {x,x+1,x+32,x+33}
// (conflict-free b128 LDS reads, 4 reads per 16 popcll). Single
// stage/sync/compute. Plain int2-coalesced stores into Cp[s]. Diagonal tiles
// also accumulate c1 (column 1-counts) via integer atomics.
// ---------------------------------------------------------------------------
__global__ __launch_bounds__(256) void gram_kernel(const u64* __restrict__ packed,
                                                   int* __restrict__ Cp,
                                                   int* __restrict__ c1) {
    __shared__ u64 ldsI[SW][64];
    __shared__ u64 ldsJ[SW][64];

    const int s = blockIdx.x & (NSLICE - 1);  // K-slice 0..31
    const int t = blockIdx.x >> 5;            // tile 0..35
    int bi = (int)((sqrtf(8.0f * (float)t + 1.0f) - 1.0f) * 0.5f);
    while ((bi + 1) * (bi + 2) / 2 <= t) ++bi;
    while (bi * (bi + 1) / 2 > t) --bi;
    const int bj = t - bi * (bi + 1) / 2;

    const int i0 = bi * 64, j0 = bj * 64;
    const int w0 = s * SW;
    const bool diag = (bi == bj);

    // stage SW words x 64 cols per side (8 KB each side)
    for (int q = threadIdx.x; q < SW * 32; q += 256) {
        const int wo = q >> 5, cp = (q & 31) * 2;
        const size_t g = (size_t)(w0 + wo) * NBITS;
        *reinterpret_cast<ulonglong2*>(&ldsI[wo][cp]) =
            *reinterpret_cast<const ulonglong2*>(&packed[g + i0 + cp]);
        if (!diag)
            *reinterpret_cast<ulonglong2*>(&ldsJ[wo][cp]) =
                *reinterpret_cast<const ulonglong2*>(&packed[g + j0 + cp]);
    }
    __syncthreads();

    const int tj2 = (threadIdx.x & 15) * 2;   // j-col base (fast dim, even)
    const int ti2 = (threadIdx.x >> 4) * 2;   // i-col base (even)
    const u64 (*BJ)[64] = diag ? ldsI : ldsJ;

    int acc[4][4] = {};
#pragma unroll
    for (int w = 0; w < SW; ++w) {
        const u64 a0 = ldsI[w][ti2],      a1 = ldsI[w][ti2 + 1];
        const u64 a2 = ldsI[w][ti2 + 32], a3 = ldsI[w][ti2 + 33];
        const u64 b0 = BJ[w][tj2],        b1 = BJ[w][tj2 + 1];
        const u64 b2 = BJ[w][tj2 + 32],   b3 = BJ[w][tj2 + 33];
        acc[0][0] += __popcll(a0 & b0); acc[0][1] += __popcll(a0 & b1);
        acc[0][2] += __popcll(a0 & b2); acc[0][3] += __popcll(a0 & b3);
        acc[1][0] += __popcll(a1 & b0); acc[1][1] += __popcll(a1 & b1);
        acc[1][2] += __popcll(a1 & b2); acc[1][3] += __popcll(a1 & b3);
        acc[2][0] += __popcll(a2 & b0); acc[2][1] += __popcll(a2 & b1);
        acc[2][2] += __popcll(a2 & b2); acc[2][3] += __popcll(a2 & b3);
        acc[3][0] += __popcll(a3 & b0); acc[3][1] += __popcll(a3 & b1);
        acc[3][2] += __popcll(a3 & b2); acc[3][3] += __popcll(a3 & b3);
    }

    int* out = Cp + (size_t)s * NBITS * NBITS;
    const int io[4] = {ti2, ti2 + 1, ti2 + 32, ti2 + 33};
#pragma unroll
    for (int a = 0; a < 4; ++a) {
        const size_t row = (size_t)(i0 + io[a]) * NBITS + j0;
        *reinterpret_cast<int2*>(&out[row + tj2])      = make_int2(acc[a][0], acc[a][1]);
        *reinterpret_cast<int2*>(&out[row + tj2 + 32]) = make_int2(acc[a][2], acc[a][3]);
    }

    // diagonal tiles: acc[a][a] of threads with ti2==tj2 are per-slice column
    // 1-counts; integer atomics (exact, order-independent).
    if (diag && ti2 == tj2) {
#pragma unroll
        for (int a = 0; a < 4; ++a)
            atomicAdd(&c1[i0 + io[a]], acc[a][a]);
    }
}

// ---------------------------------------------------------------------------
// Pass 3: per-pair MI terms. Block i, thread j (+256). n11 = coalesced sum of
// 32 slice partials of row i; marginals from c1. Log-table epilogue,
// deterministic block reduction.
// ---------------------------------------------------------------------------
__global__ __launch_bounds__(256) void mi_kernel(const int* __restrict__ Cp,
                                                 const int* __restrict__ c1,
                                                 const double* __restrict__ lg,
                                                 double* __restrict__ bsum,
                                                 int* __restrict__ bcnt) {
    const double invB = 1.0 / (double)BATCH;
    const int i = blockIdx.x;
    const int ci = c1[i];
    const double lgB = lg[BATCH];
    double lsum = 0.0;
    int lcnt = 0;

#pragma unroll
    for (int half = 0; half < 2; ++half) {
        const int j = half * 256 + threadIdx.x;
        if (j < i) {
            int n11 = 0;
#pragma unroll
            for (int s = 0; s < NSLICE; ++s)
                n11 += Cp[(size_t)s * NBITS * NBITS + (size_t)i * NBITS + j];
            const int cj = c1[j];

            const int pim[2] = {BATCH - ci, ci};
            const int pjn[2] = {BATCH - cj, cj};
            const int nmn[2][2] = {{BATCH - ci - cj + n11, cj - n11},
                                   {ci - n11, n11}};
#pragma unroll
            for (int m = 0; m < 2; ++m)
#pragma unroll
                for (int n = 0; n < 2; ++n) {
                    const int c_mn = nmn[m][n];
                    if (c_mn > 0 && pim[m] > 0 && pjn[n] > 0) {
                        lsum += (double)c_mn * invB *
                                (lg[c_mn] + lgB - lg[pim[m]] - lg[pjn[n]]);
                        ++lcnt;
                    }
                }
        }
    }

    __shared__ double ssum[256];
    __shared__ int scnt[256];
    ssum[threadIdx.x] = lsum;
    scnt[threadIdx.x] = lcnt;
    __syncthreads();
    for (int off = 128; off > 0; off >>= 1) {
        if (threadIdx.x < off) {
            ssum[threadIdx.x] += ssum[threadIdx.x + off];
            scnt[threadIdx.x] += scnt[threadIdx.x + off];
        }
        __syncthreads();
    }
    if (threadIdx.x == 0) { bsum[blockIdx.x] = ssum[0]; bcnt[blockIdx.x] = scnt[0]; }
}

// ---------------------------------------------------------------------------
// Pass 4: final deterministic reduce, out = sum / cnt.
// ---------------------------------------------------------------------------
__global__ __launch_bounds__(256) void final_kernel(const double* __restrict__ bsum,
                                                    const int* __restrict__ bcnt,
                                                    float* __restrict__ out,
                                                    int nblocks) {
    __shared__ double ssum[256];
    __shared__ int scnt[256];
    double s = 0.0; int c = 0;
    for (int k = threadIdx.x; k < nblocks; k += 256) { s += bsum[k]; c += bcnt[k]; }
    ssum[threadIdx.x] = s;
    scnt[threadIdx.x] = c;
    __syncthreads();
    for (int off = 128; off > 0; off >>= 1) {
        if (threadIdx.x < off) {
            ssum[threadIdx.x] += ssum[threadIdx.x + off];
            scnt[threadIdx.x] += scnt[threadIdx.x + off];
        }
        __syncthreads();
    }
    if (threadIdx.x == 0) out[0] = (float)(ssum[0] / (double)scnt[0]);
}

// ---------------------------------------------------------------------------
extern "C" void kernel_launch(void* const* d_in, const int* in_sizes, int n_in,
                              void* d_out, int out_size, void* d_ws, size_t ws_size,
                              hipStream_t stream) {
    const float* bits = (const float*)d_in[0];
    char* ws = (char*)d_ws;
    u64*    packed = (u64*)ws;                                  // 2 MB
    int*    Cp     = (int*)(ws + (2u << 20));                   // 32 x 1 MB
    double* lg     = (double*)(ws + (34u << 20));               // 256 KB + 8 B
    int*    c1     = (int*)(ws + (34u << 20) + (512u << 10));   // 2 KB
    double* bsum   = (double*)(ws + (34u << 20) + (576u << 10)); // 4 KB
    int*    bcnt   = (int*)(ws + (34u << 20) + (640u << 10));   // 2 KB

    pack_kernel<<<512, 256, 0, stream>>>(bits, packed, lg, c1);
    gram_kernel<<<NTILE * NSLICE, 256, 0, stream>>>(packed, Cp, c1);
    mi_kernel<<<NBITS, 256, 0, stream>>>(Cp, c1, lg, bsum, bcnt);
    final_kernel<<<1, 256, 0, stream>>>(bsum, bcnt, (float*)d_out, NBITS);
}